// Round 1
// baseline (466.205 us; speedup 1.0000x reference)
//
#include <hip/hip_runtime.h>
#include <stdint.h>

// Sparse strided conv: scatter (features@W1 -> grid) + gather (grid@W2 -> out).
// Hash-compacted grid (~363K active rows of 1.48M dense sites) => ws ~138 MiB.

#define N_VOX 120000
#define IC 32
#define OC 64
#define NKV 27
#define DZ 21
#define HY 200
#define WX 176
#define TBL_BITS 20
#define TBL_SIZE (1 << TBL_BITS)
#define TBL_MASK (TBL_SIZE - 1)
#define MAXROWS 480000
#define VPB 128

// ws layout (bytes)
#define OFF_KEYS 0
#define OFF_VALS 4194304
#define OFF_CNT 8388608
#define OFF_ROWS 8388864
#define OFF_GRID 21348864
#define WS_NEEDED (OFF_GRID + (size_t)MAXROWS * OC * 4)

__device__ __forceinline__ uint32_t hash_lin(int lin) {
    return ((uint32_t)lin * 2654435761u) >> (32 - TBL_BITS);
}

__device__ __forceinline__ void atomAddF32(float* p, float v) {
    unsafeAtomicAdd(p, v);  // global_atomic_add_f32 on gfx950
}

__global__ void k_init(int* keys, float* out, int* counter) {
    int i = blockIdx.x * blockDim.x + threadIdx.x;
    int stride = gridDim.x * blockDim.x;
    for (int j = i; j < N_VOX * IC; j += stride) out[j] = 0.f;
    for (int j = i; j < TBL_SIZE; j += stride) keys[j] = -1;
    if (i == 0) *counter = 0;
}

__global__ void k_build(const int* __restrict__ coors, int* keys, int* rows) {
    int v = blockIdx.x * blockDim.x + threadIdx.x;
    if (v >= N_VOX) return;
    int b = coors[v * 4 + 0];
    int z = coors[v * 4 + 1];
    int y = coors[v * 4 + 2];
    int x = coors[v * 4 + 3];
#pragma unroll
    for (int kv = 0; kv < NKV; ++kv) {
        int oz = kv / 9, oy = (kv / 3) % 3, ox = kv % 3;
        int az = z + 1 - oz, ay = y + 1 - oy, ax = x + 1 - ox;
        int slot = -1;
        bool valid = (az >= 0) && !(az & 1) && ((az >> 1) < DZ) &&
                     (ay >= 0) && !(ay & 1) && ((ay >> 1) < HY) &&
                     (ax >= 0) && !(ax & 1) && ((ax >> 1) < WX);
        if (valid) {
            int lin = ((b * DZ + (az >> 1)) * HY + (ay >> 1)) * WX + (ax >> 1);
            uint32_t h = hash_lin(lin);
            for (;;) {
                int k = atomicCAS(&keys[h], -1, lin);
                if (k == -1 || k == lin) { slot = (int)h; break; }
                h = (h + 1) & TBL_MASK;
            }
        }
        rows[kv * N_VOX + v] = slot;
    }
}

__global__ void k_assign(const int* __restrict__ keys, int* vals, int* counter) {
    int s = blockIdx.x * blockDim.x + threadIdx.x;
    if (s >= TBL_SIZE) return;
    if (keys[s] != -1) {
        int v = atomicAdd(counter, 1);
        vals[s] = (v < MAXROWS) ? v : -1;
    }
}

__global__ void k_zero_grid(float4* gridc4, const int* __restrict__ counter) {
    int n = min(*counter, MAXROWS) * (OC / 4);
    int i = blockIdx.x * blockDim.x + threadIdx.x;
    int stride = gridDim.x * blockDim.x;
    float4 zz = {0.f, 0.f, 0.f, 0.f};
    for (int j = i; j < n; j += stride) gridc4[j] = zz;
}

__global__ void k_rows_fix(int* rows, const int* __restrict__ vals) {
    int i = blockIdx.x * blockDim.x + threadIdx.x;
    if (i >= NKV * N_VOX) return;
    int s = rows[i];
    rows[i] = (s >= 0) ? vals[s] : -1;
}

// wave64 per voxel; lane = output channel o. W1[kv] column in 32 VGPRs.
// voxel index is wave-uniform (block=64) -> f row goes through s_load.
__global__ __launch_bounds__(64) void k_scatter(const float* __restrict__ feat,
                                                const float* __restrict__ W1,
                                                const int* __restrict__ rows,
                                                float* gridc) {
    const int kv = blockIdx.y;
    const int lane = threadIdx.x;
    float w[IC];
#pragma unroll
    for (int c = 0; c < IC; ++c) w[c] = W1[(kv * IC + c) * OC + lane];
    const int v0 = blockIdx.x * VPB;
    const int v1 = (v0 + VPB < N_VOX) ? (v0 + VPB) : N_VOX;
    const int* rkv = rows + kv * N_VOX;
    for (int v = v0; v < v1; ++v) {
        int row = rkv[v];
        if (row < 0) continue;
        const float* f = feat + v * IC;
        float acc = 0.f;
#pragma unroll
        for (int c = 0; c < IC; ++c) acc = fmaf(f[c], w[c], acc);
        atomAddF32(gridc + (size_t)row * OC + lane, acc);
    }
}

// wave64 per voxel; lane = (h, c): half h sums o in [32h, 32h+32), channel c.
// W2[kv] half-column in 32 VGPRs; halves combined via shfl_xor(32).
__global__ __launch_bounds__(64) void k_gather(const float* __restrict__ gridc,
                                               const float* __restrict__ W2,
                                               const int* __restrict__ rows,
                                               float* out) {
    const int kv = blockIdx.y;
    const int lane = threadIdx.x;
    const int h = lane >> 5;
    const int c = lane & 31;
    float w[32];
#pragma unroll
    for (int j = 0; j < 32; ++j) w[j] = W2[(kv * OC + h * 32 + j) * IC + c];
    const int v0 = blockIdx.x * VPB;
    const int v1 = (v0 + VPB < N_VOX) ? (v0 + VPB) : N_VOX;
    const int* rkv = rows + kv * N_VOX;
    for (int v = v0; v < v1; ++v) {
        int row = rkv[v];
        if (row < 0) continue;
        const float4* g4 = (const float4*)(gridc + (size_t)row * OC + h * 32);
        float acc = 0.f;
#pragma unroll
        for (int j4 = 0; j4 < 8; ++j4) {
            float4 gv = g4[j4];
            acc = fmaf(gv.x, w[j4 * 4 + 0], acc);
            acc = fmaf(gv.y, w[j4 * 4 + 1], acc);
            acc = fmaf(gv.z, w[j4 * 4 + 2], acc);
            acc = fmaf(gv.w, w[j4 * 4 + 3], acc);
        }
        acc += __shfl_xor(acc, 32, 64);
        if (lane < 32) atomAddF32(out + v * IC + c, acc);
    }
}

extern "C" void kernel_launch(void* const* d_in, const int* in_sizes, int n_in,
                              void* d_out, int out_size, void* d_ws, size_t ws_size,
                              hipStream_t stream) {
    const float* feat = (const float*)d_in[0];
    const int* coors = (const int*)d_in[1];
    const float* W1 = (const float*)d_in[2];
    const float* W2 = (const float*)d_in[3];
    float* out = (float*)d_out;

    if (ws_size < WS_NEEDED) return;  // loud failure: out stays zero

    char* ws = (char*)d_ws;
    int* keys = (int*)(ws + OFF_KEYS);
    int* vals = (int*)(ws + OFF_VALS);
    int* counter = (int*)(ws + OFF_CNT);
    int* rows = (int*)(ws + OFF_ROWS);
    float* gridc = (float*)(ws + OFF_GRID);

    k_init<<<dim3(15000), dim3(256), 0, stream>>>(keys, out, counter);
    k_build<<<dim3((N_VOX + 255) / 256), dim3(256), 0, stream>>>(coors, keys, rows);
    k_assign<<<dim3(TBL_SIZE / 256), dim3(256), 0, stream>>>(keys, vals, counter);
    k_zero_grid<<<dim3(2048), dim3(256), 0, stream>>>((float4*)gridc, counter);
    k_rows_fix<<<dim3((NKV * N_VOX + 255) / 256), dim3(256), 0, stream>>>(rows, vals);

    dim3 gs((N_VOX + VPB - 1) / VPB, NKV);
    k_scatter<<<gs, dim3(64), 0, stream>>>(feat, W1, rows, gridc);
    k_gather<<<gs, dim3(64), 0, stream>>>(gridc, W2, rows, out);
}

// Round 2
// 285.638 us; speedup vs baseline: 1.6322x; 1.6322x over previous
//
#include <hip/hip_runtime.h>
#include <stdint.h>

// Sparse strided conv: scatter (features@W1 -> grid) + gather (grid@W2 -> out).
// Hash-compacted grid (~363K active rows of 1.48M dense sites) => ws ~138 MiB.
// R2: k_assign rewritten with block-aggregated compaction (1 atomic/block,
//     was 1 atomic/wave to a single address = 188 us of serialization).

#define N_VOX 120000
#define IC 32
#define OC 64
#define NKV 27
#define DZ 21
#define HY 200
#define WX 176
#define TBL_BITS 20
#define TBL_SIZE (1 << TBL_BITS)
#define TBL_MASK (TBL_SIZE - 1)
#define MAXROWS 480000
#define VPB 128

// ws layout (bytes)
#define OFF_KEYS 0
#define OFF_VALS 4194304
#define OFF_CNT 8388608
#define OFF_ROWS 8388864
#define OFF_GRID 21348864
#define WS_NEEDED (OFF_GRID + (size_t)MAXROWS * OC * 4)

__device__ __forceinline__ uint32_t hash_lin(int lin) {
    return ((uint32_t)lin * 2654435761u) >> (32 - TBL_BITS);
}

__device__ __forceinline__ void atomAddF32(float* p, float v) {
    unsafeAtomicAdd(p, v);  // global_atomic_add_f32 on gfx950
}

__global__ void k_init(int* keys, float* out, int* counter) {
    int i = blockIdx.x * blockDim.x + threadIdx.x;
    int stride = gridDim.x * blockDim.x;
    for (int j = i; j < N_VOX * IC; j += stride) out[j] = 0.f;
    for (int j = i; j < TBL_SIZE; j += stride) keys[j] = -1;
    if (i == 0) *counter = 0;
}

__global__ void k_build(const int* __restrict__ coors, int* keys, int* rows) {
    int v = blockIdx.x * blockDim.x + threadIdx.x;
    if (v >= N_VOX) return;
    int b = coors[v * 4 + 0];
    int z = coors[v * 4 + 1];
    int y = coors[v * 4 + 2];
    int x = coors[v * 4 + 3];
#pragma unroll
    for (int kv = 0; kv < NKV; ++kv) {
        int oz = kv / 9, oy = (kv / 3) % 3, ox = kv % 3;
        int az = z + 1 - oz, ay = y + 1 - oy, ax = x + 1 - ox;
        int slot = -1;
        bool valid = (az >= 0) && !(az & 1) && ((az >> 1) < DZ) &&
                     (ay >= 0) && !(ay & 1) && ((ay >> 1) < HY) &&
                     (ax >= 0) && !(ax & 1) && ((ax >> 1) < WX);
        if (valid) {
            int lin = ((b * DZ + (az >> 1)) * HY + (ay >> 1)) * WX + (ax >> 1);
            uint32_t h = hash_lin(lin);
            for (;;) {
                int k = atomicCAS(&keys[h], -1, lin);
                if (k == -1 || k == lin) { slot = (int)h; break; }
                h = (h + 1) & TBL_MASK;
            }
        }
        rows[kv * N_VOX + v] = slot;
    }
}

// Block-aggregated compaction: 512 blocks, each owns 2048 slots; thread owns
// 8 contiguous slots (2x int4 loads); block scan in LDS; ONE atomic per block.
__global__ __launch_bounds__(256) void k_assign(const int* __restrict__ keys,
                                                int* __restrict__ vals,
                                                int* counter) {
    const int t = threadIdx.x;
    const int s0 = blockIdx.x * 2048 + t * 8;
    const int4 a = ((const int4*)(keys + s0))[0];
    const int4 b = ((const int4*)(keys + s0))[1];
    int k[8] = {a.x, a.y, a.z, a.w, b.x, b.y, b.z, b.w};
    int c = 0;
#pragma unroll
    for (int i = 0; i < 8; ++i) c += (k[i] != -1);

    __shared__ int sc[256];
    __shared__ int base;
    sc[t] = c;
    __syncthreads();
#pragma unroll
    for (int d = 1; d < 256; d <<= 1) {
        int y = (t >= d) ? sc[t - d] : 0;
        __syncthreads();
        sc[t] += y;
        __syncthreads();
    }
    if (t == 255) base = atomicAdd(counter, sc[255]);
    __syncthreads();
    int r = base + sc[t] - c;  // exclusive prefix
#pragma unroll
    for (int i = 0; i < 8; ++i) {
        if (k[i] != -1) { vals[s0 + i] = (r < MAXROWS) ? r : -1; ++r; }
    }
}

__global__ void k_zero_grid(float4* gridc4, const int* __restrict__ counter) {
    int n = min(*counter, MAXROWS) * (OC / 4);
    int i = blockIdx.x * blockDim.x + threadIdx.x;
    int stride = gridDim.x * blockDim.x;
    float4 zz = {0.f, 0.f, 0.f, 0.f};
    for (int j = i; j < n; j += stride) gridc4[j] = zz;
}

__global__ void k_rows_fix(int* rows, const int* __restrict__ vals) {
    int i = blockIdx.x * blockDim.x + threadIdx.x;
    if (i >= NKV * N_VOX) return;
    int s = rows[i];
    rows[i] = (s >= 0) ? vals[s] : -1;
}

// wave64 per voxel; lane = output channel o. W1[kv] column in 32 VGPRs.
// voxel index is wave-uniform (block=64) -> f row goes through s_load.
__global__ __launch_bounds__(64) void k_scatter(const float* __restrict__ feat,
                                                const float* __restrict__ W1,
                                                const int* __restrict__ rows,
                                                float* gridc) {
    const int kv = blockIdx.y;
    const int lane = threadIdx.x;
    float w[IC];
#pragma unroll
    for (int c = 0; c < IC; ++c) w[c] = W1[(kv * IC + c) * OC + lane];
    const int v0 = blockIdx.x * VPB;
    const int v1 = (v0 + VPB < N_VOX) ? (v0 + VPB) : N_VOX;
    const int* rkv = rows + kv * N_VOX;
    for (int v = v0; v < v1; ++v) {
        int row = rkv[v];
        if (row < 0) continue;
        const float* f = feat + v * IC;
        float acc = 0.f;
#pragma unroll
        for (int c = 0; c < IC; ++c) acc = fmaf(f[c], w[c], acc);
        atomAddF32(gridc + (size_t)row * OC + lane, acc);
    }
}

// wave64 per voxel; lane = (h, c): half h sums o in [32h, 32h+32), channel c.
// W2[kv] half-column in 32 VGPRs; halves combined via shfl_xor(32).
__global__ __launch_bounds__(64) void k_gather(const float* __restrict__ gridc,
                                               const float* __restrict__ W2,
                                               const int* __restrict__ rows,
                                               float* out) {
    const int kv = blockIdx.y;
    const int lane = threadIdx.x;
    const int h = lane >> 5;
    const int c = lane & 31;
    float w[32];
#pragma unroll
    for (int j = 0; j < 32; ++j) w[j] = W2[(kv * OC + h * 32 + j) * IC + c];
    const int v0 = blockIdx.x * VPB;
    const int v1 = (v0 + VPB < N_VOX) ? (v0 + VPB) : N_VOX;
    const int* rkv = rows + kv * N_VOX;
    for (int v = v0; v < v1; ++v) {
        int row = rkv[v];
        if (row < 0) continue;
        const float4* g4 = (const float4*)(gridc + (size_t)row * OC + h * 32);
        float acc = 0.f;
#pragma unroll
        for (int j4 = 0; j4 < 8; ++j4) {
            float4 gv = g4[j4];
            acc = fmaf(gv.x, w[j4 * 4 + 0], acc);
            acc = fmaf(gv.y, w[j4 * 4 + 1], acc);
            acc = fmaf(gv.z, w[j4 * 4 + 2], acc);
            acc = fmaf(gv.w, w[j4 * 4 + 3], acc);
        }
        acc += __shfl_xor(acc, 32, 64);
        if (lane < 32) atomAddF32(out + v * IC + c, acc);
    }
}

extern "C" void kernel_launch(void* const* d_in, const int* in_sizes, int n_in,
                              void* d_out, int out_size, void* d_ws, size_t ws_size,
                              hipStream_t stream) {
    const float* feat = (const float*)d_in[0];
    const int* coors = (const int*)d_in[1];
    const float* W1 = (const float*)d_in[2];
    const float* W2 = (const float*)d_in[3];
    float* out = (float*)d_out;

    if (ws_size < WS_NEEDED) return;  // loud failure: out stays zero

    char* ws = (char*)d_ws;
    int* keys = (int*)(ws + OFF_KEYS);
    int* vals = (int*)(ws + OFF_VALS);
    int* counter = (int*)(ws + OFF_CNT);
    int* rows = (int*)(ws + OFF_ROWS);
    float* gridc = (float*)(ws + OFF_GRID);

    k_init<<<dim3(15000), dim3(256), 0, stream>>>(keys, out, counter);
    k_build<<<dim3((N_VOX + 255) / 256), dim3(256), 0, stream>>>(coors, keys, rows);
    k_assign<<<dim3(TBL_SIZE / 2048), dim3(256), 0, stream>>>(keys, vals, counter);
    k_zero_grid<<<dim3(2048), dim3(256), 0, stream>>>((float4*)gridc, counter);
    k_rows_fix<<<dim3((NKV * N_VOX + 255) / 256), dim3(256), 0, stream>>>(rows, vals);

    dim3 gs((N_VOX + VPB - 1) / VPB, NKV);
    k_scatter<<<gs, dim3(64), 0, stream>>>(feat, W1, rows, gridc);
    k_gather<<<gs, dim3(64), 0, stream>>>(gridc, W2, rows, out);
}

// Round 3
// 281.458 us; speedup vs baseline: 1.6564x; 1.0148x over previous
//
#include <hip/hip_runtime.h>
#include <stdint.h>

// Sparse strided conv: scatter (features@W1 -> grid) + gather (grid@W2 -> out).
// R3: scatter/gather restructured: ballot-compacted pair lists in LDS
//     (vectorized row-id scan, was 128 serial scalar loads per wave = 94cy/iter)
//     + 2-deep pipelined pair processing.

#define N_VOX 120000
#define IC 32
#define OC 64
#define NKV 27
#define DZ 21
#define HY 200
#define WX 176
#define TBL_BITS 20
#define TBL_SIZE (1 << TBL_BITS)
#define TBL_MASK (TBL_SIZE - 1)
#define MAXROWS 480000
#define VPB 256  // voxels scanned per wave in scatter/gather

// ws layout (bytes)
#define OFF_KEYS 0
#define OFF_VALS 4194304
#define OFF_CNT 8388608
#define OFF_ROWS 8388864
#define OFF_GRID 21348864
#define WS_NEEDED (OFF_GRID + (size_t)MAXROWS * OC * 4)

__device__ __forceinline__ uint32_t hash_lin(int lin) {
    return ((uint32_t)lin * 2654435761u) >> (32 - TBL_BITS);
}

__device__ __forceinline__ void atomAddF32(float* p, float v) {
    unsafeAtomicAdd(p, v);  // global_atomic_add_f32 on gfx950
}

__global__ void k_init(int* keys, float* out, int* counter) {
    int i = blockIdx.x * blockDim.x + threadIdx.x;
    int stride = gridDim.x * blockDim.x;
    for (int j = i; j < N_VOX * IC; j += stride) out[j] = 0.f;
    for (int j = i; j < TBL_SIZE; j += stride) keys[j] = -1;
    if (i == 0) *counter = 0;
}

__global__ void k_build(const int* __restrict__ coors, int* keys, int* rows) {
    int v = blockIdx.x * blockDim.x + threadIdx.x;
    if (v >= N_VOX) return;
    int b = coors[v * 4 + 0];
    int z = coors[v * 4 + 1];
    int y = coors[v * 4 + 2];
    int x = coors[v * 4 + 3];
#pragma unroll
    for (int kv = 0; kv < NKV; ++kv) {
        int oz = kv / 9, oy = (kv / 3) % 3, ox = kv % 3;
        int az = z + 1 - oz, ay = y + 1 - oy, ax = x + 1 - ox;
        int slot = -1;
        bool valid = (az >= 0) && !(az & 1) && ((az >> 1) < DZ) &&
                     (ay >= 0) && !(ay & 1) && ((ay >> 1) < HY) &&
                     (ax >= 0) && !(ax & 1) && ((ax >> 1) < WX);
        if (valid) {
            int lin = ((b * DZ + (az >> 1)) * HY + (ay >> 1)) * WX + (ax >> 1);
            uint32_t h = hash_lin(lin);
            for (;;) {
                int k = atomicCAS(&keys[h], -1, lin);
                if (k == -1 || k == lin) { slot = (int)h; break; }
                h = (h + 1) & TBL_MASK;
            }
        }
        rows[kv * N_VOX + v] = slot;
    }
}

// Block-aggregated compaction: ONE atomic per block (R2 fix).
__global__ __launch_bounds__(256) void k_assign(const int* __restrict__ keys,
                                                int* __restrict__ vals,
                                                int* counter) {
    const int t = threadIdx.x;
    const int s0 = blockIdx.x * 2048 + t * 8;
    const int4 a = ((const int4*)(keys + s0))[0];
    const int4 b = ((const int4*)(keys + s0))[1];
    int k[8] = {a.x, a.y, a.z, a.w, b.x, b.y, b.z, b.w};
    int c = 0;
#pragma unroll
    for (int i = 0; i < 8; ++i) c += (k[i] != -1);

    __shared__ int sc[256];
    __shared__ int base;
    sc[t] = c;
    __syncthreads();
#pragma unroll
    for (int d = 1; d < 256; d <<= 1) {
        int y = (t >= d) ? sc[t - d] : 0;
        __syncthreads();
        sc[t] += y;
        __syncthreads();
    }
    if (t == 255) base = atomicAdd(counter, sc[255]);
    __syncthreads();
    int r = base + sc[t] - c;  // exclusive prefix
#pragma unroll
    for (int i = 0; i < 8; ++i) {
        if (k[i] != -1) { vals[s0 + i] = (r < MAXROWS) ? r : -1; ++r; }
    }
}

__global__ void k_zero_grid(float4* gridc4, const int* __restrict__ counter) {
    int n = min(*counter, MAXROWS) * (OC / 4);
    int i = blockIdx.x * blockDim.x + threadIdx.x;
    int stride = gridDim.x * blockDim.x;
    float4 zz = {0.f, 0.f, 0.f, 0.f};
    for (int j = i; j < n; j += stride) gridc4[j] = zz;
}

__global__ void k_rows_fix(int* rows, const int* __restrict__ vals) {
    int i = blockIdx.x * blockDim.x + threadIdx.x;
    if (i >= NKV * N_VOX) return;
    int s = rows[i];
    rows[i] = (s >= 0) ? vals[s] : -1;
}

// Ballot-compact valid (v,row) pairs of this wave's VPB voxels into LDS.
// Returns pair count. 1 wave per block -> no __syncthreads needed.
__device__ __forceinline__ int compact_pairs(const int* __restrict__ rkv,
                                             int v0, int lane,
                                             int* ls_v, int* ls_r) {
    int n = 0;
#pragma unroll
    for (int ch = 0; ch < VPB / 64; ++ch) {
        int v = v0 + ch * 64 + lane;
        int row = (v < N_VOX) ? rkv[v] : -1;
        unsigned long long m = __ballot(row >= 0);
        int pos = n + (int)__popcll(m & ((1ULL << lane) - 1));
        if (row >= 0) { ls_v[pos] = v; ls_r[pos] = row; }
        n += (int)__popcll(m);
    }
    return n;
}

// wave64 per pair-batch; lane = output channel o. W1[kv] column in 32 VGPRs.
// Pairs processed 2 at a time: both feature rows loaded (uniform broadcast
// float4s) before either dot product -> counted-vmcnt overlap.
__global__ __launch_bounds__(64) void k_scatter(const float* __restrict__ feat,
                                                const float* __restrict__ W1,
                                                const int* __restrict__ rows,
                                                float* gridc) {
    const int kv = blockIdx.y;
    const int lane = threadIdx.x;
    __shared__ int ls_v[VPB];
    __shared__ int ls_r[VPB];

    float w[IC];
#pragma unroll
    for (int c = 0; c < IC; ++c) w[c] = W1[(kv * IC + c) * OC + lane];

    const int n = compact_pairs(rows + kv * N_VOX, blockIdx.x * VPB, lane,
                                ls_v, ls_r);

    for (int p = 0; p < n; p += 2) {
        const bool hasB = (p + 1 < n);
        const int ia = p, ib = hasB ? p + 1 : p;
        const int vA = ls_v[ia], rA = ls_r[ia];
        const int vB = ls_v[ib], rB = ls_r[ib];
        const float4* pA = (const float4*)(feat + (size_t)vA * IC);
        const float4* pB = (const float4*)(feat + (size_t)vB * IC);
        float4 fA[8], fB[8];
#pragma unroll
        for (int j = 0; j < 8; ++j) { fA[j] = pA[j]; fB[j] = pB[j]; }
        float accA = 0.f, accB = 0.f;
#pragma unroll
        for (int j = 0; j < 8; ++j) {
            accA = fmaf(fA[j].x, w[4 * j + 0], accA);
            accA = fmaf(fA[j].y, w[4 * j + 1], accA);
            accA = fmaf(fA[j].z, w[4 * j + 2], accA);
            accA = fmaf(fA[j].w, w[4 * j + 3], accA);
            accB = fmaf(fB[j].x, w[4 * j + 0], accB);
            accB = fmaf(fB[j].y, w[4 * j + 1], accB);
            accB = fmaf(fB[j].z, w[4 * j + 2], accB);
            accB = fmaf(fB[j].w, w[4 * j + 3], accB);
        }
        atomAddF32(gridc + (size_t)rA * OC + lane, accA);
        if (hasB) atomAddF32(gridc + (size_t)rB * OC + lane, accB);
    }
}

// wave64 per pair-batch; lane = (h, c): half h covers o in [32h,32h+32).
// W2[kv] half-column in 32 VGPRs; halves combined via shfl_xor(32).
__global__ __launch_bounds__(64) void k_gather(const float* __restrict__ gridc,
                                               const float* __restrict__ W2,
                                               const int* __restrict__ rows,
                                               float* out) {
    const int kv = blockIdx.y;
    const int lane = threadIdx.x;
    const int h = lane >> 5;
    const int c = lane & 31;
    __shared__ int ls_v[VPB];
    __shared__ int ls_r[VPB];

    float w[32];
#pragma unroll
    for (int j = 0; j < 32; ++j) w[j] = W2[(kv * OC + h * 32 + j) * IC + c];

    const int n = compact_pairs(rows + kv * N_VOX, blockIdx.x * VPB, lane,
                                ls_v, ls_r);

    for (int p = 0; p < n; p += 2) {
        const bool hasB = (p + 1 < n);
        const int ia = p, ib = hasB ? p + 1 : p;
        const int vA = ls_v[ia], rA = ls_r[ia];
        const int vB = ls_v[ib], rB = ls_r[ib];
        const float4* pA = (const float4*)(gridc + (size_t)rA * OC + h * 32);
        const float4* pB = (const float4*)(gridc + (size_t)rB * OC + h * 32);
        float4 gA[8], gB[8];
#pragma unroll
        for (int j = 0; j < 8; ++j) { gA[j] = pA[j]; gB[j] = pB[j]; }
        float accA = 0.f, accB = 0.f;
#pragma unroll
        for (int j = 0; j < 8; ++j) {
            accA = fmaf(gA[j].x, w[4 * j + 0], accA);
            accA = fmaf(gA[j].y, w[4 * j + 1], accA);
            accA = fmaf(gA[j].z, w[4 * j + 2], accA);
            accA = fmaf(gA[j].w, w[4 * j + 3], accA);
            accB = fmaf(gB[j].x, w[4 * j + 0], accB);
            accB = fmaf(gB[j].y, w[4 * j + 1], accB);
            accB = fmaf(gB[j].z, w[4 * j + 2], accB);
            accB = fmaf(gB[j].w, w[4 * j + 3], accB);
        }
        accA += __shfl_xor(accA, 32, 64);
        accB += __shfl_xor(accB, 32, 64);
        if (lane < 32) {
            atomAddF32(out + vA * IC + c, accA);
            if (hasB) atomAddF32(out + vB * IC + c, accB);
        }
    }
}

extern "C" void kernel_launch(void* const* d_in, const int* in_sizes, int n_in,
                              void* d_out, int out_size, void* d_ws, size_t ws_size,
                              hipStream_t stream) {
    const float* feat = (const float*)d_in[0];
    const int* coors = (const int*)d_in[1];
    const float* W1 = (const float*)d_in[2];
    const float* W2 = (const float*)d_in[3];
    float* out = (float*)d_out;

    if (ws_size < WS_NEEDED) return;  // loud failure: out stays zero

    char* ws = (char*)d_ws;
    int* keys = (int*)(ws + OFF_KEYS);
    int* vals = (int*)(ws + OFF_VALS);
    int* counter = (int*)(ws + OFF_CNT);
    int* rows = (int*)(ws + OFF_ROWS);
    float* gridc = (float*)(ws + OFF_GRID);

    k_init<<<dim3(15000), dim3(256), 0, stream>>>(keys, out, counter);
    k_build<<<dim3((N_VOX + 255) / 256), dim3(256), 0, stream>>>(coors, keys, rows);
    k_assign<<<dim3(TBL_SIZE / 2048), dim3(256), 0, stream>>>(keys, vals, counter);
    k_zero_grid<<<dim3(2048), dim3(256), 0, stream>>>((float4*)gridc, counter);
    k_rows_fix<<<dim3((NKV * N_VOX + 255) / 256), dim3(256), 0, stream>>>(rows, vals);

    dim3 gs((N_VOX + VPB - 1) / VPB, NKV);
    k_scatter<<<gs, dim3(64), 0, stream>>>(feat, W1, rows, gridc);
    k_gather<<<gs, dim3(64), 0, stream>>>(gridc, W2, rows, out);
}